// Round 7
// baseline (150.792 us; speedup 1.0000x reference)
//
#include <hip/hip_runtime.h>
#include <hip/hip_bf16.h>

#define BATCH 64
#define NADJ  512
#define F     128
#define CROP0 128
#define CROP1 384
#define CN    256
#define BN_EPS 1e-5f

// Instrumentation: in-kernel idempotent repeats so each kernel's dispatch
// exceeds the ~39us harness-fill cutoff and surfaces in rocprof top-5 with
// its own counters. Single-shot time = dur / REPS (reps 2+ are cache-warm:
// if dur/REPS << prior cold estimates, kernel is HBM-latency-bound).
#define K1REP 10
#define K2REP 6
#define K3REP 10

typedef __attribute__((ext_vector_type(8))) short short8;
typedef __attribute__((ext_vector_type(4))) float f32x4;

__device__ __forceinline__ ushort f2bf(float x) {
  __hip_bfloat16 h = __float2bfloat16(x);  // RNE
  return *reinterpret_cast<ushort*>(&h);
}

// XCD-aligned swizzle (kept from R6; free)
__device__ __forceinline__ void swz(int W, int& b, int& t0) {
  const int x = W & 7, y = W >> 3;
  b  = ((y >> 3) << 3) | x;
  t0 = (y & 7) * 32;
}

// ---------------------------------------------------------------------------
// K1: St[b][f][m] = bf16( (input_crop @ W)^T ), m-tile 32 per block.
// ---------------------------------------------------------------------------
__global__ __launch_bounds__(256) void support_k(
    const float* __restrict__ input, const float* __restrict__ W,
    ushort* __restrict__ St) {
  int b, m0;
  swz(blockIdx.x, b, m0);
  __shared__ ushort wt[128][136];  // W^T [f][i]
  __shared__ ushort ain[32][136];  // input tile [m][i]
  const int tid = threadIdx.x;
  const float* inb = input + ((size_t)b * NADJ + CROP0 + m0) * F;

  for (int rep = 0; rep < K1REP; ++rep) {
    asm volatile("" ::: "memory");
    __syncthreads();
    // stage W^T: thread covers i=(tid&63)+{0,64}, f=(tid>>6)*32..+32
    {
      const int i0 = tid & 63;
      const int fq = (tid >> 6) * 32;
#pragma unroll
      for (int ih = 0; ih < 2; ++ih) {
        const int i = i0 + ih * 64;
        const float* wr = &W[(size_t)i * F + fq];
        float4 v[8];
#pragma unroll
        for (int q = 0; q < 8; ++q)
          v[q] = reinterpret_cast<const float4*>(wr)[q];
#pragma unroll
        for (int q = 0; q < 8; ++q) {
          wt[fq + q * 4 + 0][i] = f2bf(v[q].x);
          wt[fq + q * 4 + 1][i] = f2bf(v[q].y);
          wt[fq + q * 4 + 2][i] = f2bf(v[q].z);
          wt[fq + q * 4 + 3][i] = f2bf(v[q].w);
        }
      }
    }
    for (int idx = tid; idx < 32 * 32; idx += 256) {
      const int ml = idx >> 5, c4 = (idx & 31) * 4;
      const float4 v =
          *reinterpret_cast<const float4*>(&inb[(size_t)ml * F + c4]);
      *reinterpret_cast<ushort4*>(&ain[ml][c4]) =
          make_ushort4(f2bf(v.x), f2bf(v.y), f2bf(v.z), f2bf(v.w));
    }
    __syncthreads();

    const int l = tid & 63, w = tid >> 6;
    const int lr = l & 15, lg = l >> 4;
    const int msub = (w & 1) * 16;
    const int f0   = (w >> 1) * 64;
    f32x4 acc[4] = {};
#pragma unroll
    for (int ks = 0; ks < 4; ++ks) {
      const int k0 = ks * 32 + lg * 8;
      const short8 av = *reinterpret_cast<const short8*>(&ain[msub + lr][k0]);
#pragma unroll
      for (int fi = 0; fi < 4; ++fi) {
        const short8 bv =
            *reinterpret_cast<const short8*>(&wt[f0 + fi * 16 + lr][k0]);
        acc[fi] =
            __builtin_amdgcn_mfma_f32_16x16x32_bf16(av, bv, acc[fi], 0, 0, 0);
      }
    }
#pragma unroll
    for (int fi = 0; fi < 4; ++fi) {
      const int f = f0 + fi * 16 + lr;
      *reinterpret_cast<ushort4*>(
          &St[((size_t)b * F + f) * CN + m0 + msub + lg * 4]) =
          make_ushort4(f2bf(acc[fi][0]), f2bf(acc[fi][1]), f2bf(acc[fi][2]),
                       f2bf(acc[fi][3]));
    }
  }
}

// ---------------------------------------------------------------------------
// K2: Ocrop[b][n][f] = adj_crop[b][n][:] @ S[b][:][f]  (dense 8.4MB output)
// ---------------------------------------------------------------------------
__global__ __launch_bounds__(256) void aggregate_k(
    const float* __restrict__ adj, const ushort* __restrict__ St,
    float* __restrict__ Ocrop) {
  int b, n0;
  swz(blockIdx.x, b, n0);
  __shared__ ushort adt[32][264];
  const int tid = threadIdx.x;
  const float* adjb = adj + ((size_t)b * NADJ + CROP0 + n0) * NADJ + CROP0;
  const ushort* Stb = St + (size_t)b * F * CN;

  for (int rep = 0; rep < K2REP; ++rep) {
    asm volatile("" ::: "memory");
    __syncthreads();
    for (int idx = tid; idx < 32 * 64; idx += 256) {
      const int nl = idx >> 6, c4 = (idx & 63) * 4;
      const float4 v =
          *reinterpret_cast<const float4*>(&adjb[(size_t)nl * NADJ + c4]);
      *reinterpret_cast<ushort4*>(&adt[nl][c4]) =
          make_ushort4(f2bf(v.x), f2bf(v.y), f2bf(v.z), f2bf(v.w));
    }
    __syncthreads();

    const int l = tid & 63, w = tid >> 6;
    const int lr = l & 15, lg = l >> 4;
    const int nsub = (w & 1) * 16;
    const int f0   = (w >> 1) * 64;
    f32x4 acc[4] = {};
#pragma unroll 4
    for (int ks = 0; ks < 8; ++ks) {
      const int k0 = ks * 32 + lg * 8;
      const short8 av = *reinterpret_cast<const short8*>(&adt[nsub + lr][k0]);
#pragma unroll
      for (int fi = 0; fi < 4; ++fi) {
        const short8 bv = *reinterpret_cast<const short8*>(
            &Stb[(size_t)(f0 + fi * 16 + lr) * CN + k0]);
        acc[fi] =
            __builtin_amdgcn_mfma_f32_16x16x32_bf16(av, bv, acc[fi], 0, 0, 0);
      }
    }
#pragma unroll
    for (int fi = 0; fi < 4; ++fi) {
      const int f = f0 + fi * 16 + lr;
      const int n = n0 + nsub + lg * 4;
#pragma unroll
      for (int r = 0; r < 4; ++r)
        Ocrop[((size_t)b * CN + n + r) * F + f] = acc[fi][r];
    }
  }
}

// ---------------------------------------------------------------------------
// K3: BN stats + normalize from dense Ocrop -> full out write + beta-fill.
// Pure function Ocrop -> out (idempotent).
// ---------------------------------------------------------------------------
__global__ __launch_bounds__(256) void bn_fused(
    const float* __restrict__ Ocrop, float* __restrict__ out,
    const float* __restrict__ gamma, const float* __restrict__ beta) {
  __shared__ float s_l[256], s2_l[256], m_l[64], r_l[64];
  const int tid = threadIdx.x;
  const int jl = tid & 63, bg = tid >> 6;
  const int j  = blockIdx.x * 64 + jl;  // 0..32767 = nl*128+f
  const int nl = j >> 7, f = j & 127;
  const int nf = (CROP0 + nl) * F + f;
  const float* p = Ocrop + (size_t)j + (size_t)bg * 16 * CN * F;

  for (int rep = 0; rep < K3REP; ++rep) {
    asm volatile("" ::: "memory");
    __syncthreads();
    float x[16];
    float s = 0.f, s2 = 0.f;
#pragma unroll
    for (int bb = 0; bb < 16; ++bb) {
      x[bb] = p[(size_t)bb * CN * F];
      s += x[bb];
      s2 += x[bb] * x[bb];
    }
    s_l[tid]  = s;
    s2_l[tid] = s2;
    __syncthreads();
    if (tid < 64) {
      s  = s_l[jl] + s_l[64 + jl] + s_l[128 + jl] + s_l[192 + jl];
      s2 = s2_l[jl] + s2_l[64 + jl] + s2_l[128 + jl] + s2_l[192 + jl];
      const float mean = s * (1.f / BATCH);
      const float var  = s2 * (1.f / BATCH) - mean * mean;
      m_l[jl] = mean;
      r_l[jl] = rsqrtf(var + BN_EPS);
    }
    __syncthreads();
    const float mean = m_l[jl];
    const float a    = r_l[jl] * gamma[nf];
    const float c    = beta[nf] - mean * a;
#pragma unroll
    for (int bb = 0; bb < 16; ++bb)
      out[(size_t)nf + (size_t)(bg * 16 + bb) * NADJ * F] = x[bb] * a + c;

    // beta-fill the non-crop rows
    const int gid0 = blockIdx.x * 256 + tid;
#pragma unroll
    for (int q = 0; q < 4; ++q) {
      const int gid = gid0 + q * 131072;
      const int c4  = (gid & 31) * 4;
      const int rr  = (gid >> 5) & 255;
      const int bb  = gid >> 13;
      const int n   = rr < 128 ? rr : rr + 256;
      const float4 bv =
          *reinterpret_cast<const float4*>(&beta[(size_t)n * F + c4]);
      *reinterpret_cast<float4*>(&out[((size_t)bb * NADJ + n) * F + c4]) = bv;
    }
  }
}

extern "C" void kernel_launch(void* const* d_in, const int* in_sizes, int n_in,
                              void* d_out, int out_size, void* d_ws,
                              size_t ws_size, hipStream_t stream) {
  const float* input = (const float*)d_in[0];
  const float* adj   = (const float*)d_in[1];
  const float* W     = (const float*)d_in[2];
  const float* gamma = (const float*)d_in[3];
  const float* beta  = (const float*)d_in[4];
  float* out = (float*)d_out;

  ushort* St    = (ushort*)d_ws;                            // 4 MB
  float*  Ocrop = (float*)((char*)d_ws + 4 * 1024 * 1024);  // 8.4 MB

  support_k<<<512, 256, 0, stream>>>(input, W, St);
  aggregate_k<<<512, 256, 0, stream>>>(adj, St, Ocrop);
  bn_fused<<<512, 256, 0, stream>>>(Ocrop, out, gamma, beta);
}

// Round 8
// 31.757 us; speedup vs baseline: 4.7483x; 4.7483x over previous
//
#include <hip/hip_runtime.h>
#include <hip/hip_bf16.h>

#define BATCH 64
#define NADJ  512
#define F     128
#define CROP0 128
#define CROP1 384
#define CN    256
#define BN_EPS 1e-5f

typedef __attribute__((ext_vector_type(8))) short short8;
typedef __attribute__((ext_vector_type(4))) float f32x4;

__device__ __forceinline__ ushort f2bf(float x) {
  __hip_bfloat16 h = __float2bfloat16(x);  // RNE
  return *reinterpret_cast<ushort*>(&h);
}

// XCD-aligned swizzle: all 8 tiles of batch b land on XCD (b&7) so St[b]
// stays in one XCD's private L2 across K1 (write) and K2 (read).
__device__ __forceinline__ void swz(int W, int& b, int& t0) {
  const int x = W & 7, y = W >> 3;
  b  = ((y >> 3) << 3) | x;
  t0 = (y & 7) * 32;
}

// ---------------------------------------------------------------------------
// K1: St[b][f][m] = bf16( (input_crop @ W)^T ), m-tile 32 per block.
// Also beta-fills the non-crop rows of out (K1 is latency-idle; free).
// ---------------------------------------------------------------------------
__global__ __launch_bounds__(256) void support_k(
    const float* __restrict__ input, const float* __restrict__ W,
    ushort* __restrict__ St, float* __restrict__ out,
    const float* __restrict__ beta) {
  int b, m0;
  swz(blockIdx.x, b, m0);
  __shared__ ushort wt[128][136];  // W^T [f][i]
  __shared__ ushort ain[32][136];  // input tile [m][i]
  const int tid = threadIdx.x;
  const float* inb = input + ((size_t)b * NADJ + CROP0 + m0) * F;

  // stage W^T: thread covers i=(tid&63)+{0,64}, f=(tid>>6)*32..+32
  {
    const int i0 = tid & 63;
    const int fq = (tid >> 6) * 32;
#pragma unroll
    for (int ih = 0; ih < 2; ++ih) {
      const int i = i0 + ih * 64;
      const float* wr = &W[(size_t)i * F + fq];
      float4 v[8];
#pragma unroll
      for (int q = 0; q < 8; ++q)
        v[q] = reinterpret_cast<const float4*>(wr)[q];
#pragma unroll
      for (int q = 0; q < 8; ++q) {
        wt[fq + q * 4 + 0][i] = f2bf(v[q].x);
        wt[fq + q * 4 + 1][i] = f2bf(v[q].y);
        wt[fq + q * 4 + 2][i] = f2bf(v[q].z);
        wt[fq + q * 4 + 3][i] = f2bf(v[q].w);
      }
    }
  }
  for (int idx = tid; idx < 32 * 32; idx += 256) {
    const int ml = idx >> 5, c4 = (idx & 31) * 4;
    const float4 v =
        *reinterpret_cast<const float4*>(&inb[(size_t)ml * F + c4]);
    *reinterpret_cast<ushort4*>(&ain[ml][c4]) =
        make_ushort4(f2bf(v.x), f2bf(v.y), f2bf(v.z), f2bf(v.w));
  }
  __syncthreads();

  const int l = tid & 63, w = tid >> 6;
  const int lr = l & 15, lg = l >> 4;
  const int msub = (w & 1) * 16;
  const int f0   = (w >> 1) * 64;
  f32x4 acc[4] = {};
#pragma unroll
  for (int ks = 0; ks < 4; ++ks) {
    const int k0 = ks * 32 + lg * 8;
    const short8 av = *reinterpret_cast<const short8*>(&ain[msub + lr][k0]);
#pragma unroll
    for (int fi = 0; fi < 4; ++fi) {
      const short8 bv =
          *reinterpret_cast<const short8*>(&wt[f0 + fi * 16 + lr][k0]);
      acc[fi] =
          __builtin_amdgcn_mfma_f32_16x16x32_bf16(av, bv, acc[fi], 0, 0, 0);
    }
  }
#pragma unroll
  for (int fi = 0; fi < 4; ++fi) {
    const int f = f0 + fi * 16 + lr;
    *reinterpret_cast<ushort4*>(
        &St[((size_t)b * F + f) * CN + m0 + msub + lg * 4]) =
        make_ushort4(f2bf(acc[fi][0]), f2bf(acc[fi][1]), f2bf(acc[fi][2]),
                     f2bf(acc[fi][3]));
  }

  // beta-fill non-crop rows of out (independent region; 512x256 threads x4)
  const int gid = blockIdx.x * 256 + tid;
#pragma unroll
  for (int q = 0; q < 4; ++q) {
    const int g2 = gid + q * 131072;
    const int c4 = (g2 & 31) * 4;
    const int rr = (g2 >> 5) & 255;
    const int bb = g2 >> 13;
    const int n  = rr < 128 ? rr : rr + 256;
    const float4 bv =
        *reinterpret_cast<const float4*>(&beta[(size_t)n * F + c4]);
    *reinterpret_cast<float4*>(&out[((size_t)bb * NADJ + n) * F + c4]) = bv;
  }
}

// ---------------------------------------------------------------------------
// K2: Ocrop[b][n][f] = adj_crop[b][n][:] @ S[b][:][f], n-tile 32 per block.
// T14: adj + St-chunk loads issued early to regs; St double-buffered in LDS;
// B-frags from LDS (144B row stride: conflict-free). 53.8KB LDS -> 3 blk/CU.
// ---------------------------------------------------------------------------
__global__ __launch_bounds__(256) void aggregate_k(
    const float* __restrict__ adj, const ushort* __restrict__ St,
    float* __restrict__ Ocrop) {
  int b, n0;
  swz(blockIdx.x, b, n0);
  __shared__ ushort adt[32][264];     // adj tile bf16 [n][k], 528B stride
  __shared__ ushort stl[2][128][72];  // St chunk dbuf [f][kl], 144B stride
  const int tid = threadIdx.x;
  const float* adjb = adj + ((size_t)b * NADJ + CROP0 + n0) * NADJ + CROP0;
  const ushort* Stb = St + (size_t)b * F * CN;

  // issue adj tile loads (32x256 fp32): 8 x float4 per thread, coalesced
  const int ar = tid >> 6;         // row group 0..3
  const int ac = (tid & 63) * 4;   // col
  float4 areg[8];
#pragma unroll
  for (int q = 0; q < 8; ++q)
    areg[q] = *reinterpret_cast<const float4*>(
        &adjb[(size_t)(ar + q * 4) * NADJ + ac]);
  // issue St chunk0 loads (128 x 64 bf16): 4 x uint4 per thread
  const int sr = tid >> 3;         // 0..31
  const int sc = (tid & 7) * 8;    // ushort col (16B)
  uint4 sreg[4];
#pragma unroll
  for (int j = 0; j < 4; ++j)
    sreg[j] = *reinterpret_cast<const uint4*>(
        &Stb[(size_t)(sr + j * 32) * CN + sc]);
  // write both to LDS
#pragma unroll
  for (int q = 0; q < 8; ++q)
    *reinterpret_cast<ushort4*>(&adt[ar + q * 4][ac]) =
        make_ushort4(f2bf(areg[q].x), f2bf(areg[q].y), f2bf(areg[q].z),
                     f2bf(areg[q].w));
#pragma unroll
  for (int j = 0; j < 4; ++j)
    *reinterpret_cast<uint4*>(&stl[0][sr + j * 32][sc]) = sreg[j];
  __syncthreads();

  const int l = tid & 63, w = tid >> 6;
  const int lr = l & 15, lg = l >> 4;
  const int nsub = (w & 1) * 16;
  const int f0   = (w >> 1) * 64;
  f32x4 acc[4] = {};

  for (int c = 0; c < 4; ++c) {
    // issue next-chunk loads (fire-and-forget; consumed after MFMA phase)
    uint4 nreg[4];
    if (c < 3) {
#pragma unroll
      for (int j = 0; j < 4; ++j)
        nreg[j] = *reinterpret_cast<const uint4*>(
            &Stb[(size_t)(sr + j * 32) * CN + (c + 1) * 64 + sc]);
    }
    const int cb = c & 1;
#pragma unroll
    for (int ks = 0; ks < 2; ++ks) {
      const int kl = ks * 32 + lg * 8;
      const short8 av =
          *reinterpret_cast<const short8*>(&adt[nsub + lr][c * 64 + kl]);
#pragma unroll
      for (int fi = 0; fi < 4; ++fi) {
        const short8 bv = *reinterpret_cast<const short8*>(
            &stl[cb][f0 + fi * 16 + lr][kl]);
        acc[fi] =
            __builtin_amdgcn_mfma_f32_16x16x32_bf16(av, bv, acc[fi], 0, 0, 0);
      }
    }
    __syncthreads();
    if (c < 3) {
#pragma unroll
      for (int j = 0; j < 4; ++j)
        *reinterpret_cast<uint4*>(&stl[cb ^ 1][sr + j * 32][sc]) = nreg[j];
    }
    __syncthreads();
  }

#pragma unroll
  for (int fi = 0; fi < 4; ++fi) {
    const int f = f0 + fi * 16 + lr;
    const int n = n0 + nsub + lg * 4;
#pragma unroll
    for (int r = 0; r < 4; ++r)
      Ocrop[((size_t)b * CN + n + r) * F + f] = acc[fi][r];
  }
}

// ---------------------------------------------------------------------------
// K3: BN stats + normalize from dense Ocrop -> out crop rows only.
// ---------------------------------------------------------------------------
__global__ __launch_bounds__(256) void bn_crop(
    const float* __restrict__ Ocrop, float* __restrict__ out,
    const float* __restrict__ gamma, const float* __restrict__ beta) {
  __shared__ float s_l[256], s2_l[256], m_l[64], r_l[64];
  const int tid = threadIdx.x;
  const int jl = tid & 63, bg = tid >> 6;
  const int j  = blockIdx.x * 64 + jl;  // 0..32767 = nl*128+f
  const int nl = j >> 7, f = j & 127;
  const int nf = (CROP0 + nl) * F + f;
  const float* p = Ocrop + (size_t)j + (size_t)bg * 16 * CN * F;

  float x[16];
  float s = 0.f, s2 = 0.f;
#pragma unroll
  for (int bb = 0; bb < 16; ++bb) {
    x[bb] = p[(size_t)bb * CN * F];
    s += x[bb];
    s2 += x[bb] * x[bb];
  }
  s_l[tid]  = s;
  s2_l[tid] = s2;
  __syncthreads();
  if (tid < 64) {
    s  = s_l[jl] + s_l[64 + jl] + s_l[128 + jl] + s_l[192 + jl];
    s2 = s2_l[jl] + s2_l[64 + jl] + s2_l[128 + jl] + s2_l[192 + jl];
    const float mean = s * (1.f / BATCH);
    const float var  = s2 * (1.f / BATCH) - mean * mean;
    m_l[jl] = mean;
    r_l[jl] = rsqrtf(var + BN_EPS);
  }
  __syncthreads();
  const float mean = m_l[jl];
  const float a    = r_l[jl] * gamma[nf];
  const float c    = beta[nf] - mean * a;
#pragma unroll
  for (int bb = 0; bb < 16; ++bb)
    out[(size_t)nf + (size_t)(bg * 16 + bb) * NADJ * F] = x[bb] * a + c;
}

extern "C" void kernel_launch(void* const* d_in, const int* in_sizes, int n_in,
                              void* d_out, int out_size, void* d_ws,
                              size_t ws_size, hipStream_t stream) {
  const float* input = (const float*)d_in[0];
  const float* adj   = (const float*)d_in[1];
  const float* W     = (const float*)d_in[2];
  const float* gamma = (const float*)d_in[3];
  const float* beta  = (const float*)d_in[4];
  float* out = (float*)d_out;

  ushort* St    = (ushort*)d_ws;                            // 4 MB
  float*  Ocrop = (float*)((char*)d_ws + 4 * 1024 * 1024);  // 8.4 MB

  support_k<<<512, 256, 0, stream>>>(input, W, St, out, beta);
  aggregate_k<<<512, 256, 0, stream>>>(adj, St, Ocrop);
  bn_crop<<<512, 256, 0, stream>>>(Ocrop, out, gamma, beta);
}